// Round 8
// baseline (9448.275 us; speedup 1.0000x reference)
//
#include <hip/hip_runtime.h>
#include <hip/hip_fp16.h>

// Persistent 2D-LSTM, self-validating tagged-ring protocol (no fences/flags).
// B=64, NC=512, T=1024, K=1216 = [x 0..191 | h(t-32) 192..703 | h(t-1) 704..1215].
// 4 batch-groups x 64 col-WGs = 256 WGs x 512 thr (1 WG/CU, 112.5KB LDS).
// WG (g,w): batches g*16..+15, channels w*8..+7 (x4 gates = 32 gate-cols).
// h ring: fp16 [slot 64][g 4][b 16][ch 512]; u64 = 4 ch. Each fp16's LSB is
// forced to generation parity ((t>>6)&1): consumers poll data until tags match.
// Ring pre-memset to 0x01 bytes (LSB=1) != gen-0 parity (0).
// r8 timing: h(t-1) issued at step top (validated after x/h32 MFMAs);
// x/h(t-32) prefetched for t+1 BEFORE the barrier, validated at use.

typedef __attribute__((ext_vector_type(8))) _Float16 half8;
typedef __attribute__((ext_vector_type(4))) float f32x4;
typedef unsigned long long u64;

#define T_ 1024

#define LDS_W    77824              // 38 chunks * 2 tiles * 64 lanes * 16B
#define LDS_PSM  36864              // f32 [2][8][16][36]
#define LDS_ALL  (LDS_W + LDS_PSM + 512)

extern __shared__ char smem[];

union U2H { u64 u[2]; half8 h; };

__global__ __launch_bounds__(512, 2) void lstm_persist(
    const float* __restrict__ x, const float* __restrict__ Wih,
    const float* __restrict__ Whh, const float* __restrict__ bih,
    const float* __restrict__ bhh, float* __restrict__ out,
    u64* ring)
{
    _Float16* Wsm = (_Float16*)smem;
    float*    Psm = (float*)(smem + LDS_W);
    float*    cst = (float*)(smem + LDS_W + LDS_PSM);

    const int tid = threadIdx.x;
    const int l   = tid & 63, wv = tid >> 6;
    const int l15 = l & 15,  l4 = l >> 4;
    const int bid = blockIdx.x;
    const int g   = bid >> 6;          // batch group 0..3
    const int w   = bid & 63;          // channel WG 0..63

    // ---- weights fp32 -> fp16 fragments in LDS (once) ----
    // tile col co = nb*16 + l15: gate = l15&3, ch_local = nb*4 + (l15>>2)
    for (int p = wv; p < 76; p += 8) {
        const int c = p >> 1, nb = p & 1;
        const int rj = (l15 & 3) * 512 + w * 8 + nb * 4 + (l15 >> 2);
        const int k  = c * 32 + l4 * 8;
        const float* src = (c < 22) ? (Wih + (size_t)rj * 704 + k)
                                    : (Whh + (size_t)rj * 512 + (k - 704));
        float4 v0 = ((const float4*)src)[0];
        float4 v1 = ((const float4*)src)[1];
        half8 hb;
        hb[0]=(_Float16)v0.x; hb[1]=(_Float16)v0.y; hb[2]=(_Float16)v0.z; hb[3]=(_Float16)v0.w;
        hb[4]=(_Float16)v1.x; hb[5]=(_Float16)v1.y; hb[6]=(_Float16)v1.z; hb[7]=(_Float16)v1.w;
        *(half8*)(Wsm + (size_t)((c * 2 + nb) * 64 + l) * 8) = hb;
    }
    if (tid < 128) cst[tid] = 0.f;

    // pointwise role (tid<128): pb = batch 0..15, pc = channel 0..7
    const int pb = tid >> 3, pc = tid & 7;
    const int gc = w * 8 + pc;
    const float bI = bih[gc]        + bhh[gc];
    const float bF = bih[512 + gc]  + bhh[512 + gc];
    const float bG = bih[1024 + gc] + bhh[1024 + gc];
    const float bO = bih[1536 + gc] + bhh[1536 + gc];
    __syncthreads();

    const int coff = (wv + 2) & 7;       // wave's h-chunk offset
    const int gb   = g * 16 + l15;       // A-row batch
    const int rcb  = coff * 8 + l4 * 2;  // ring u64 col base ('a' frag; 'b' at +64)

    auto wfrag = [&](int c, int nb) -> half8 {
        return *(const half8*)(Wsm + (size_t)((c * 2 + nb) * 64 + l) * 8);
    };
    auto rld = [&](size_t i) -> u64 {
        return __hip_atomic_load(ring + i, __ATOMIC_RELAXED, __HIP_MEMORY_SCOPE_AGENT);
    };
    const u64 TM = 0x0001000100010001ULL;

    // prefetch register state
    float4 xa0 = {0,0,0,0}, xa1 = {0,0,0,0};
    u64 h32a0 = 0, h32a1 = 0, h32b0 = 0, h32b1 = 0;   // h(t-32) raw prefetch
    u64 h1a0, h1a1, h1b0, h1b1;                        // h(t-1) early issue

    // prologue: x for t=0 (y=0, xc=0)
    if (wv < 6) {
        const int k0 = wv * 32 + l4 * 8;
        const float* xs = x + ((size_t)(gb * 3 + (k0 >> 6)) * 256 + ((k0 >> 3) & 7)) * 256;
        xa0 = ((const float4*)xs)[0];
        xa1 = ((const float4*)xs)[1];
    }

    for (int t = 0; t < T_; ++t) {
        const int par = t & 1;
        f32x4 acc0 = {0.f,0.f,0.f,0.f}, acc1 = {0.f,0.f,0.f,0.f};

        // [A0] early-issue h(t-1) loads (fire-and-forget; validated at [C])
        size_t iaP = 0;
        if (t > 0) {
            iaP = ((size_t)(((t - 1) & 63) * 4 + g) * 16 + l15) * 128 + rcb;
            h1a0 = rld(iaP);      h1a1 = rld(iaP + 1);
            h1b0 = rld(iaP + 64); h1b1 = rld(iaP + 65);
        }

        // [A] x part (prefetched regs; validated-by-construction)
        if (wv < 6) {
            half8 a;
            a[0]=(_Float16)xa0.x; a[1]=(_Float16)xa0.y; a[2]=(_Float16)xa0.z; a[3]=(_Float16)xa0.w;
            a[4]=(_Float16)xa1.x; a[5]=(_Float16)xa1.y; a[6]=(_Float16)xa1.z; a[7]=(_Float16)xa1.w;
            acc0 = __builtin_amdgcn_mfma_f32_16x16x32_f16(a, wfrag(wv,0), acc0, 0,0,0);
            acc1 = __builtin_amdgcn_mfma_f32_16x16x32_f16(a, wfrag(wv,1), acc1, 0,0,0);
        }

        // [B] h(t-32): validate raw-prefetched regs, rare retry, MFMA
        if (t >= 32) {
            const u64 ex = (((t - 32) >> 6) & 1) ? TM : 0ULL;
            bool ok = ((h32a0 & TM) == ex) && ((h32a1 & TM) == ex) &&
                      ((h32b0 & TM) == ex) && ((h32b1 & TM) == ex);
            if (!__all(ok)) {
                const size_t ia = ((size_t)((((t - 32) & 63)) * 4 + g) * 16 + l15) * 128 + rcb;
                do {
                    if (!ok) {
                        h32a0 = rld(ia);      h32a1 = rld(ia + 1);
                        h32b0 = rld(ia + 64); h32b1 = rld(ia + 65);
                        ok = ((h32a0 & TM) == ex) && ((h32a1 & TM) == ex) &&
                             ((h32b0 & TM) == ex) && ((h32b1 & TM) == ex);
                    }
                } while (!__all(ok));
            }
            U2H ca, cb;
            ca.u[0] = h32a0; ca.u[1] = h32a1;
            cb.u[0] = h32b0; cb.u[1] = h32b1;
            acc0 = __builtin_amdgcn_mfma_f32_16x16x32_f16(ca.h, wfrag(6+coff,0),  acc0, 0,0,0);
            acc1 = __builtin_amdgcn_mfma_f32_16x16x32_f16(ca.h, wfrag(6+coff,1),  acc1, 0,0,0);
            acc0 = __builtin_amdgcn_mfma_f32_16x16x32_f16(cb.h, wfrag(14+coff,0), acc0, 0,0,0);
            acc1 = __builtin_amdgcn_mfma_f32_16x16x32_f16(cb.h, wfrag(14+coff,1), acc1, 0,0,0);
        }

        // [C] h(t-1): validate early-issued regs, retry until tagged, MFMA
        if (t > 0) {
            const u64 ex = (((t - 1) >> 6) & 1) ? TM : 0ULL;
            bool ok = ((h1a0 & TM) == ex) && ((h1a1 & TM) == ex) &&
                      ((h1b0 & TM) == ex) && ((h1b1 & TM) == ex);
            while (!__all(ok)) {
                if (!ok) {
                    h1a0 = rld(iaP);      h1a1 = rld(iaP + 1);
                    h1b0 = rld(iaP + 64); h1b1 = rld(iaP + 65);
                    ok = ((h1a0 & TM) == ex) && ((h1a1 & TM) == ex) &&
                         ((h1b0 & TM) == ex) && ((h1b1 & TM) == ex);
                }
            }
            U2H ca, cb;
            ca.u[0] = h1a0; ca.u[1] = h1a1;
            cb.u[0] = h1b0; cb.u[1] = h1b1;
            acc0 = __builtin_amdgcn_mfma_f32_16x16x32_f16(ca.h, wfrag(22+coff,0), acc0, 0,0,0);
            acc1 = __builtin_amdgcn_mfma_f32_16x16x32_f16(ca.h, wfrag(22+coff,1), acc1, 0,0,0);
            acc0 = __builtin_amdgcn_mfma_f32_16x16x32_f16(cb.h, wfrag(30+coff,0), acc0, 0,0,0);
            acc1 = __builtin_amdgcn_mfma_f32_16x16x32_f16(cb.h, wfrag(30+coff,1), acc1, 0,0,0);
        }

        // [D] partials -> LDS (parity double-buffer)
        {
            float* Pw = Psm + (size_t)((par * 8 + wv) * 16) * 36;
#pragma unroll
            for (int r = 0; r < 4; ++r) {
                Pw[(l4 * 4 + r) * 36 + l15]      = acc0[r];
                Pw[(l4 * 4 + r) * 36 + 16 + l15] = acc1[r];
            }
        }

        // [P] prefetch for t+1 (issued BEFORE the barrier => covered by [E]+[F])
        const int tn = t + 1;
        if (tn < T_) {
            if (wv < 6) {
                const int yn = tn >> 5, xcn = tn & 31;
                const int k0 = wv * 32 + l4 * 8;
                const float* xs = x + ((size_t)(gb * 3 + (k0 >> 6)) * 256
                                       + yn * 8 + ((k0 >> 3) & 7)) * 256 + xcn * 8;
                xa0 = ((const float4*)xs)[0];
                xa1 = ((const float4*)xs)[1];
            }
            if (tn >= 32) {
                const size_t ia = ((size_t)(((tn - 32) & 63) * 4 + g) * 16 + l15) * 128 + rcb;
                h32a0 = rld(ia);      h32a1 = rld(ia + 1);
                h32b0 = rld(ia + 64); h32b1 = rld(ia + 65);
            }
        }

        __syncthreads();   // [E] one barrier per step

        // [F] pointwise + tagged publish (waves 0-1); waves 2-7 run ahead
        if (tid < 128) {
            __builtin_amdgcn_s_setprio(1);
            float gi = bI, gf = bF, gg = bG, go = bO;
#pragma unroll
            for (int q = 0; q < 8; ++q) {
                const float4 q4 = *(const float4*)(Psm
                    + (size_t)((par * 8 + q) * 16 + pb) * 36 + pc * 4);
                gi += q4.x; gf += q4.y; gg += q4.z; go += q4.w;
            }
            const float cprev = cst[tid];
            const float si = 1.f / (1.f + __expf(-gi));
            const float sf = 1.f / (1.f + __expf(-gf));
            const float so = 1.f / (1.f + __expf(-go));
            const float tg = 2.f / (1.f + __expf(-2.f * gg)) - 1.f;
            const float cn = sf * cprev + si * tg;
            const float th = 2.f / (1.f + __expf(-2.f * cn)) - 1.f;
            const float hn = so * th;
            cst[tid] = cn;

            union { _Float16 f; unsigned short s; } cv; cv.f = (_Float16)hn;
            unsigned hb16 = ((unsigned)cv.s & ~1u) | (unsigned)((t >> 6) & 1);  // force tag
            unsigned other = (unsigned)__shfl_xor((int)hb16, 1);
            unsigned pairv = (pc & 1) ? ((other & 0xffffu) | (hb16 << 16))
                                      : ((hb16 & 0xffffu) | (other << 16));
            unsigned hi = (unsigned)__shfl_xor((int)pairv, 2);
            if ((pc & 3) == 0) {
                u64 val = (u64)pairv | ((u64)hi << 32);
                const size_t idx = ((size_t)((t & 63) * 4 + g) * 16 + pb) * 128
                                 + w * 2 + (pc >> 2);
                __hip_atomic_store(ring + idx, val, __ATOMIC_RELAXED,
                                   __HIP_MEMORY_SCOPE_AGENT);
            }
            out[(size_t)(g * 16 + pb) * (T_ * 512) + (size_t)t * 512 + gc] = hn;
            __builtin_amdgcn_s_setprio(0);
        }
    }
}

extern "C" void kernel_launch(void* const* d_in, const int* in_sizes, int n_in,
                              void* d_out, int out_size, void* d_ws, size_t ws_size,
                              hipStream_t stream) {
    const float* x   = (const float*)d_in[0];
    const float* Wih = (const float*)d_in[1];
    const float* Whh = (const float*)d_in[2];
    const float* bih = (const float*)d_in[3];
    const float* bhh = (const float*)d_in[4];
    float* out = (float*)d_out;

    u64* ring = (u64*)d_ws;   // 64*4*16*128 u64 = 4 MB

    // LSB pattern 1 everywhere != gen-0 parity 0
    hipMemsetAsync(ring, 0x01, 64ull * 4 * 16 * 128 * 8, stream);

    (void)hipFuncSetAttribute((const void*)lstm_persist,
                              hipFuncAttributeMaxDynamicSharedMemorySize, LDS_ALL);

    hipLaunchKernelGGL(lstm_persist, dim3(256), dim3(512), LDS_ALL, stream,
                       x, Wih, Whh, bih, bhh, out, ring);
}

// Round 9
// 3522.869 us; speedup vs baseline: 2.6820x; 2.6820x over previous
//
#include <hip/hip_runtime.h>
#include <hip/hip_fp16.h>

// Persistent 2D-LSTM, self-validating tagged-ring protocol (no fences/flags).
// B=64, NC=512, T=1024, K=1216 = [x 0..191 | h(t-32) 192..703 | h(t-1) 704..1215].
// 4 batch-groups x 64 col-WGs = 256 WGs x 512 thr (1 WG/CU, 112KB LDS).
// WG (g,w): batches g*16..+15, channels w*8..+7 (x4 gates = 32 gate-cols).
// h ring: fp16 [slot 64][g 4][b 16][ch 512]; u64 = 4 ch. Each fp16's LSB is
// forced to generation parity ((t>>6)&1): consumers poll data until tags match.
// Ring pre-memset to 0x01 bytes (LSB=1) != gen-0 parity (0).
// r9 = r6 + ONE change: h(t-32) prefetch is fire-and-forget raw loads at [G/H],
// tag-validated at use in [B] (removes the blocking ~900cy poll from the tail).

typedef __attribute__((ext_vector_type(8))) _Float16 half8;
typedef __attribute__((ext_vector_type(4))) float f32x4;
typedef unsigned long long u64;

#define T_ 1024

#define LDS_W    77824              // 38 chunks * 2 tiles * 64 lanes * 16B
#define LDS_PSM  33792              // f32 [2][8][16][33]
#define LDS_ALL  (LDS_W + LDS_PSM + 512)

extern __shared__ char smem[];

union U2H { u64 u[2]; half8 h; };

__global__ __launch_bounds__(512, 1) void lstm_persist(
    const float* __restrict__ x, const float* __restrict__ Wih,
    const float* __restrict__ Whh, const float* __restrict__ bih,
    const float* __restrict__ bhh, float* __restrict__ out,
    u64* ring)
{
    _Float16* Wsm = (_Float16*)smem;
    float*    Psm = (float*)(smem + LDS_W);
    float*    cst = (float*)(smem + LDS_W + LDS_PSM);

    const int tid = threadIdx.x;
    const int l   = tid & 63, wv = tid >> 6;
    const int l15 = l & 15,  l4 = l >> 4;
    const int bid = blockIdx.x;
    const int g   = bid >> 6;          // batch group 0..3
    const int w   = bid & 63;          // channel WG 0..63

    // ---- weights fp32 -> fp16 fragments in LDS (once) ----
    // tile col co = nb*16 + l15: gate = l15&3, ch_local = nb*4 + (l15>>2)
    for (int p = wv; p < 76; p += 8) {
        const int c = p >> 1, nb = p & 1;
        const int rj = (l15 & 3) * 512 + w * 8 + nb * 4 + (l15 >> 2);
        const int k  = c * 32 + l4 * 8;
        const float* src = (c < 22) ? (Wih + (size_t)rj * 704 + k)
                                    : (Whh + (size_t)rj * 512 + (k - 704));
        float4 v0 = ((const float4*)src)[0];
        float4 v1 = ((const float4*)src)[1];
        half8 hb;
        hb[0]=(_Float16)v0.x; hb[1]=(_Float16)v0.y; hb[2]=(_Float16)v0.z; hb[3]=(_Float16)v0.w;
        hb[4]=(_Float16)v1.x; hb[5]=(_Float16)v1.y; hb[6]=(_Float16)v1.z; hb[7]=(_Float16)v1.w;
        *(half8*)(Wsm + (size_t)((c * 2 + nb) * 64 + l) * 8) = hb;
    }
    if (tid < 128) cst[tid] = 0.f;

    // pointwise role (tid<128): pb = batch 0..15, pc = channel 0..7
    const int pb = tid >> 3, pc = tid & 7;
    const int gc = w * 8 + pc;
    const float bI = bih[gc]        + bhh[gc];
    const float bF = bih[512 + gc]  + bhh[512 + gc];
    const float bG = bih[1024 + gc] + bhh[1024 + gc];
    const float bO = bih[1536 + gc] + bhh[1536 + gc];
    __syncthreads();

    // per-wave chunk ownership
    const int coff = (wv + 2) & 7;
    const int gb   = g * 16 + l15;       // A-row batch
    const int rcb  = coff * 8 + l4 * 2;  // ring u64 col base ('a' frag; 'b' at +64)

    auto wfrag = [&](int c, int nb) -> half8 {
        return *(const half8*)(Wsm + (size_t)((c * 2 + nb) * 64 + l) * 8);
    };
    auto rld = [&](size_t i) -> u64 {
        return __hip_atomic_load(ring + i, __ATOMIC_RELAXED, __HIP_MEMORY_SCOPE_AGENT);
    };
    const u64 TM = 0x0001000100010001ULL;

    // blocking tagged fragment-pair load (h(t-1) path, unchanged from r6)
    auto loadfrag2 = [&](size_t ia, unsigned par_, half8& ha, half8& hb) {
        const u64 ex = par_ ? TM : 0ULL;
        u64 a0 = 0, a1 = 0, b0 = 0, b1 = 0;
        bool ok = false;
        do {
            if (!ok) {
                a0 = rld(ia);      a1 = rld(ia + 1);
                b0 = rld(ia + 64); b1 = rld(ia + 65);
                ok = ((a0 & TM) == ex) && ((a1 & TM) == ex) &&
                     ((b0 & TM) == ex) && ((b1 & TM) == ex);
            }
        } while (!__all(ok));
        U2H ca, cb;
        ca.u[0] = a0; ca.u[1] = a1; cb.u[0] = b0; cb.u[1] = b1;
        ha = ca.h; hb = cb.h;
    };

    float4 xa0, xa1;
    u64 h32a0 = 0, h32a1 = 0, h32b0 = 0, h32b1 = 0;   // h(t-32) raw prefetch

    if (wv < 6) {   // x prefetch for t=0 (y=0, xc=0)
        const int k0 = wv * 32 + l4 * 8;
        const float* xs = x + ((size_t)(gb * 3 + (k0 >> 6)) * 256 + ((k0 >> 3) & 7)) * 256;
        xa0 = ((const float4*)xs)[0];
        xa1 = ((const float4*)xs)[1];
    }

    for (int t = 0; t < T_; ++t) {
        const int par = t & 1;
        f32x4 acc0 = {0.f,0.f,0.f,0.f}, acc1 = {0.f,0.f,0.f,0.f};

        // [A] x part (prefetched regs)
        if (wv < 6) {
            half8 a;
            a[0]=(_Float16)xa0.x; a[1]=(_Float16)xa0.y; a[2]=(_Float16)xa0.z; a[3]=(_Float16)xa0.w;
            a[4]=(_Float16)xa1.x; a[5]=(_Float16)xa1.y; a[6]=(_Float16)xa1.z; a[7]=(_Float16)xa1.w;
            acc0 = __builtin_amdgcn_mfma_f32_16x16x32_f16(a, wfrag(wv,0), acc0, 0,0,0);
            acc1 = __builtin_amdgcn_mfma_f32_16x16x32_f16(a, wfrag(wv,1), acc1, 0,0,0);
        }
        // [B] h(t-32): validate raw-prefetched regs (rare retry), then MFMA
        if (t >= 32) {
            const u64 ex = (((t - 32) >> 6) & 1) ? TM : 0ULL;
            bool ok = ((h32a0 & TM) == ex) && ((h32a1 & TM) == ex) &&
                      ((h32b0 & TM) == ex) && ((h32b1 & TM) == ex);
            if (!__all(ok)) {
                const size_t ia = ((size_t)(((t - 32) & 63) * 4 + g) * 16 + l15) * 128 + rcb;
                do {
                    if (!ok) {
                        h32a0 = rld(ia);      h32a1 = rld(ia + 1);
                        h32b0 = rld(ia + 64); h32b1 = rld(ia + 65);
                        ok = ((h32a0 & TM) == ex) && ((h32a1 & TM) == ex) &&
                             ((h32b0 & TM) == ex) && ((h32b1 & TM) == ex);
                    }
                } while (!__all(ok));
            }
            U2H ca, cb;
            ca.u[0] = h32a0; ca.u[1] = h32a1;
            cb.u[0] = h32b0; cb.u[1] = h32b1;
            acc0 = __builtin_amdgcn_mfma_f32_16x16x32_f16(ca.h, wfrag(6+coff,0),  acc0, 0,0,0);
            acc1 = __builtin_amdgcn_mfma_f32_16x16x32_f16(ca.h, wfrag(6+coff,1),  acc1, 0,0,0);
            acc0 = __builtin_amdgcn_mfma_f32_16x16x32_f16(cb.h, wfrag(14+coff,0), acc0, 0,0,0);
            acc1 = __builtin_amdgcn_mfma_f32_16x16x32_f16(cb.h, wfrag(14+coff,1), acc1, 0,0,0);
        }
        // [C] h(t-1): blocking tagged load (issued here, as in r6 -- no early issue)
        if (t > 0) {
            const size_t iaP = ((size_t)(((t - 1) & 63) * 4 + g) * 16 + l15) * 128 + rcb;
            half8 ha, hb;
            loadfrag2(iaP, ((t - 1) >> 6) & 1, ha, hb);
            acc0 = __builtin_amdgcn_mfma_f32_16x16x32_f16(ha, wfrag(22+coff,0), acc0, 0,0,0);
            acc1 = __builtin_amdgcn_mfma_f32_16x16x32_f16(ha, wfrag(22+coff,1), acc1, 0,0,0);
            acc0 = __builtin_amdgcn_mfma_f32_16x16x32_f16(hb, wfrag(30+coff,0), acc0, 0,0,0);
            acc1 = __builtin_amdgcn_mfma_f32_16x16x32_f16(hb, wfrag(30+coff,1), acc1, 0,0,0);
        }

        // [D] partials -> LDS (parity double-buffer)
        {
            float* Pw = Psm + (size_t)((par * 8 + wv) * 16) * 33;
#pragma unroll
            for (int r = 0; r < 4; ++r) {
                Pw[(l4 * 4 + r) * 33 + l15]      = acc0[r];
                Pw[(l4 * 4 + r) * 33 + 16 + l15] = acc1[r];
            }
        }
        __syncthreads();   // [E] the only barrier per step

        // [F] pointwise + tagged publish (waves 0-1); waves 2-7 run ahead
        if (tid < 128) {
            float gi = bI, gf = bF, gg = bG, go = bO;
#pragma unroll
            for (int q = 0; q < 8; ++q) {
                const float* Pq = Psm + ((size_t)((par * 8 + q) * 16 + pb)) * 33 + pc * 4;
                gi += Pq[0]; gf += Pq[1]; gg += Pq[2]; go += Pq[3];
            }
            const float cprev = cst[tid];
            const float si = 1.f / (1.f + __expf(-gi));
            const float sf = 1.f / (1.f + __expf(-gf));
            const float so = 1.f / (1.f + __expf(-go));
            const float tg = 2.f / (1.f + __expf(-2.f * gg)) - 1.f;
            const float cn = sf * cprev + si * tg;
            const float th = 2.f / (1.f + __expf(-2.f * cn)) - 1.f;
            const float hn = so * th;
            cst[tid] = cn;

            union { _Float16 f; unsigned short s; } cv; cv.f = (_Float16)hn;
            unsigned hb16 = ((unsigned)cv.s & ~1u) | (unsigned)((t >> 6) & 1);  // force tag
            unsigned other = (unsigned)__shfl_xor((int)hb16, 1);
            unsigned pairv = (pc & 1) ? ((other & 0xffffu) | (hb16 << 16))
                                      : ((hb16 & 0xffffu) | (other << 16));
            unsigned hi = (unsigned)__shfl_xor((int)pairv, 2);
            if ((pc & 3) == 0) {
                u64 val = (u64)pairv | ((u64)hi << 32);
                const size_t idx = ((size_t)((t & 63) * 4 + g) * 16 + pb) * 128
                                 + w * 2 + (pc >> 2);
                __hip_atomic_store(ring + idx, val, __ATOMIC_RELAXED,
                                   __HIP_MEMORY_SCOPE_AGENT);
            }
            out[(size_t)(g * 16 + pb) * (T_ * 512) + (size_t)t * 512 + gc] = hn;
        }

        // [G/H] prefetch next step: x (blocking-free) and h(t+1-32) raw issue
        const int tn = t + 1;
        if (tn < T_) {
            if (wv < 6) {
                const int yn = tn >> 5, xcn = tn & 31;
                const int k0 = wv * 32 + l4 * 8;
                const float* xs = x + ((size_t)(gb * 3 + (k0 >> 6)) * 256
                                       + yn * 8 + ((k0 >> 3) & 7)) * 256 + xcn * 8;
                xa0 = ((const float4*)xs)[0];
                xa1 = ((const float4*)xs)[1];
            }
            if (tn >= 32) {
                const size_t ia = ((size_t)(((tn - 32) & 63) * 4 + g) * 16 + l15) * 128 + rcb;
                h32a0 = rld(ia);      h32a1 = rld(ia + 1);
                h32b0 = rld(ia + 64); h32b1 = rld(ia + 65);
            }
        }
    }
}

extern "C" void kernel_launch(void* const* d_in, const int* in_sizes, int n_in,
                              void* d_out, int out_size, void* d_ws, size_t ws_size,
                              hipStream_t stream) {
    const float* x   = (const float*)d_in[0];
    const float* Wih = (const float*)d_in[1];
    const float* Whh = (const float*)d_in[2];
    const float* bih = (const float*)d_in[3];
    const float* bhh = (const float*)d_in[4];
    float* out = (float*)d_out;

    u64* ring = (u64*)d_ws;   // 64*4*16*128 u64 = 4 MB

    // LSB pattern 1 everywhere != gen-0 parity 0
    hipMemsetAsync(ring, 0x01, 64ull * 4 * 16 * 128 * 8, stream);

    (void)hipFuncSetAttribute((const void*)lstm_persist,
                              hipFuncAttributeMaxDynamicSharedMemorySize, LDS_ALL);

    hipLaunchKernelGGL(lstm_persist, dim3(256), dim3(512), LDS_ALL, stream,
                       x, Wih, Whh, bih, bhh, out, ring);
}